// Round 9
// baseline (536.043 us; speedup 1.0000x reference)
//
#include <hip/hip_runtime.h>

#define NN 50000
#define NN64 50048
#define NE 600000
#define CC 128
#define SCANB 196  // ceil(NN/256)

typedef float f32x4 __attribute__((ext_vector_type(4)));
typedef float f32x2 __attribute__((ext_vector_type(2)));
typedef short bf16x8 __attribute__((ext_vector_type(8)));
typedef unsigned short u16x4 __attribute__((ext_vector_type(4)));
typedef unsigned short u16x8 __attribute__((ext_vector_type(8)));
typedef _Float16 f16x2 __attribute__((ext_vector_type(2)));
typedef _Float16 f16x4 __attribute__((ext_vector_type(4)));
typedef _Float16 f16x8 __attribute__((ext_vector_type(8)));

#if defined(__has_builtin)
#if __has_builtin(__builtin_amdgcn_fdot2)
#define HAS_FDOT2 1
#endif
#endif

__device__ __forceinline__ unsigned short f2b(float f) {
  union { float f; unsigned int u; } c; c.f = f;
  unsigned int r = c.u + 0x7FFFu + ((c.u >> 16) & 1u);
  return (unsigned short)(r >> 16);
}
// async global->LDS 16B DMA (wave-uniform LDS base + lane*16 semantics; layouts kept linear)
__device__ __forceinline__ void gload16(const unsigned short* g, unsigned short* l) {
  __builtin_amdgcn_global_load_lds((const __attribute__((address_space(1))) void*)g,
                                   (__attribute__((address_space(3))) void*)l, 16, 0, 0);
}

// ---------------- weight prep ----------------
// wpack: [chunk 0..2][ wih_c | whh_c ], each 128x128: [j][k ^ ((j&7)<<3)]  (bf16)
// cpack: [layer 0..1][j][k ^ ((j&7)<<3)]  (bf16; convW[layer] is [k][j])
// ewpk : [kp 0..7][ch 0..127] half2 = (eW[2kp][ch], eW[2kp+1][ch])  (f16)
__global__ __launch_bounds__(256) void k_prep(const float* __restrict__ wih,
                                              const float* __restrict__ whh,
                                              const float* __restrict__ convW,
                                              const float* __restrict__ eW,
                                              unsigned short* __restrict__ wpack,
                                              unsigned short* __restrict__ cpack,
                                              f16x2* __restrict__ ewpk) {
  int i = blockIdx.x * 256 + threadIdx.x;
  if (i < 98304) {
    int k = i & 127, j = (i >> 7) & 127, half = (i >> 14) & 1, chunk = i >> 15;
    const float* srcm = half ? whh : wih;
    float v = srcm[(long)(chunk * 128 + j) * CC + k];
    wpack[(long)(((chunk * 2 + half) * 128 + j) << 7) + (k ^ ((j & 7) << 3))] = f2b(v);
  } else if (i < 131072) {
    int i2 = i - 98304;
    int k = i2 & 127, j = (i2 >> 7) & 127, layer = i2 >> 14;
    float v = convW[(long)(layer * 128 + k) * CC + j];
    cpack[(long)((layer * 128 + j) << 7) + (k ^ ((j & 7) << 3))] = f2b(v);
  } else if (i < 132096) {
    int i2 = i - 131072;
    int kp = i2 >> 7, ch = i2 & 127;
    f16x2 w; w.x = (_Float16)eW[(2 * kp) * CC + ch]; w.y = (_Float16)eW[(2 * kp + 1) * CC + ch];
    ewpk[i2] = w;
  }
}

// ---------------- BatchNorm ----------------
__global__ __launch_bounds__(128) void k_bnstats(const float* __restrict__ x,
                                                 float* __restrict__ stats) {
  int c = threadIdx.x;
  float s = 0.f, s2 = 0.f;
  for (int r = blockIdx.x; r < NN; r += gridDim.x) {
    float v = x[(long)r * CC + c];
    s += v; s2 += v * v;
  }
  atomicAdd(&stats[c], s);
  atomicAdd(&stats[CC + c], s2);
}

__global__ __launch_bounds__(128) void k_bnfinal(float* __restrict__ stats,
                                                 const float* __restrict__ gamma,
                                                 const float* __restrict__ beta) {
  int c = threadIdx.x;
  float mean = stats[c] * (1.f / NN);
  float var = stats[CC + c] * (1.f / NN) - mean * mean;
  var = fmaxf(var, 0.f);
  float sc = gamma[c] * rsqrtf(var + 1e-5f);
  stats[2 * CC + c] = sc;
  stats[3 * CC + c] = beta[c] - mean * sc;
}

// writes xh (f32) + xh_b (bf16, row-swizzled, for MFMA DMA staging)
__global__ __launch_bounds__(256) void k_norm(const float* __restrict__ x,
                                              const float* __restrict__ stats,
                                              float* __restrict__ xh,
                                              unsigned short* __restrict__ xhb) {
  const int total4 = NN * CC / 4;
  for (int i = blockIdx.x * 256 + threadIdx.x; i < total4; i += gridDim.x * 256) {
    f32x4 v = ((const f32x4*)x)[i];
    int c4 = (i & 31) * 4;
    int r = i >> 5;
    f32x4 sc = *(const f32x4*)&stats[2 * CC + c4];
    f32x4 sh = *(const f32x4*)&stats[3 * CC + c4];
    v = v * sc + sh;
    ((f32x4*)xh)[i] = v;
    u16x4 b; b.x = f2b(v[0]); b.y = f2b(v[1]); b.z = f2b(v[2]); b.w = f2b(v[3]);
    *(u16x4*)&xhb[(long)r * CC + (c4 ^ ((r & 7) << 3))] = b;
  }
}

// ---------------- CSR build ----------------
__global__ __launch_bounds__(256) void k_cnt(const int* __restrict__ dst, int* __restrict__ cnt) {
  for (int e = blockIdx.x * 256 + threadIdx.x; e < NE; e += gridDim.x * 256)
    atomicAdd(&cnt[dst[e]], 1);
}

// 3-phase multi-block exclusive scan of cnt[NN] -> rowp[NN+1]
__global__ __launch_bounds__(256) void k_scan_a(const int* __restrict__ cnt,
                                                int* __restrict__ blocksum) {
  int t = threadIdx.x, b = blockIdx.x;
  int idx = b * 256 + t;
  int v = (idx < NN) ? cnt[idx] : 0;
#pragma unroll
  for (int off = 32; off; off >>= 1) v += __shfl_down(v, off, 64);
  __shared__ int wsum[4];
  if ((t & 63) == 0) wsum[t >> 6] = v;
  __syncthreads();
  if (t == 0) blocksum[b] = wsum[0] + wsum[1] + wsum[2] + wsum[3];
}

__global__ __launch_bounds__(256) void k_scan_b(const int* __restrict__ blocksum,
                                                int* __restrict__ blockoff,
                                                int* __restrict__ rowp) {
  int t = threadIdx.x;
  int v = (t < SCANB) ? blocksum[t] : 0;
  __shared__ int sd[256];
  sd[t] = v;
  __syncthreads();
  for (int off = 1; off < 256; off <<= 1) {
    int x = (t >= off) ? sd[t - off] : 0;
    __syncthreads();
    sd[t] += x;
    __syncthreads();
  }
  blockoff[t] = sd[t] - v;  // exclusive
  if (t == 255) rowp[NN] = sd[255];
}

__global__ __launch_bounds__(256) void k_scan_c(const int* __restrict__ cnt,
                                                const int* __restrict__ blockoff,
                                                int* __restrict__ rowp) {
  int t = threadIdx.x, b = blockIdx.x;
  int idx = b * 256 + t;
  int v = (idx < NN) ? cnt[idx] : 0;
  __shared__ int sd[256];
  sd[t] = v;
  __syncthreads();
  for (int off = 1; off < 256; off <<= 1) {
    int x = (t >= off) ? sd[t - off] : 0;
    __syncthreads();
    sd[t] += x;
    __syncthreads();
  }
  if (idx < NN) rowp[idx] = blockoff[b] + sd[t] - v;
}

// per edge: write src and f16 edge_attr into CSR (dst-sorted) slots
__global__ __launch_bounds__(256) void k_fill(const int* __restrict__ dst,
                                              const int* __restrict__ src,
                                              const float* __restrict__ eattr,
                                              const int* __restrict__ rowp,
                                              int* __restrict__ cursor,
                                              int* __restrict__ src_csr,
                                              _Float16* __restrict__ attr_csr) {
  for (int e = blockIdx.x * 256 + threadIdx.x; e < NE; e += gridDim.x * 256) {
    int d = dst[e];
    int pos = atomicAdd(&cursor[d], 1);
    int idx = rowp[d] + pos;
    src_csr[idx] = src[e];
    const f32x4* ar = (const f32x4*)(eattr + (long)e * 16);
    f32x4 a0 = ar[0], a1 = ar[1], a2 = ar[2], a3 = ar[3];
    f16x8 h0, h1;
#pragma unroll
    for (int q = 0; q < 4; ++q) { h0[q] = (_Float16)a0[q]; h0[4 + q] = (_Float16)a1[q]; }
#pragma unroll
    for (int q = 0; q < 4; ++q) { h1[q] = (_Float16)a2[q]; h1[4 + q] = (_Float16)a3[q]; }
    f16x8* orow = (f16x8*)&attr_csr[(long)idx * 16];
    orow[0] = h0; orow[1] = h1;
  }
}

// ---------------- m = h @ convW  (bf16 MFMA, BM=64, staging via global_load_lds, f16 out) ----------------
__global__ __launch_bounds__(256) void k_mgemm(const unsigned short* __restrict__ Ab,
                                               const unsigned short* __restrict__ Bp,
                                               _Float16* __restrict__ O) {
  __shared__ __align__(16) unsigned short As[64 * 128];   // 16KB
  __shared__ __align__(16) unsigned short Bs[128 * 128];  // 32KB
  int tid = threadIdx.x;
  int blockRow = blockIdx.x * 64;
  const unsigned short* asrc = Ab + (long)blockRow * CC;
#pragma unroll
  for (int p = 0; p < 4; ++p) {
    int off8 = (p * 256 + tid) * 8;
    gload16(asrc + off8, As + off8);
  }
#pragma unroll
  for (int p = 0; p < 8; ++p) {
    int off8 = (p * 256 + tid) * 8;
    gload16(Bp + off8, Bs + off8);
  }
  __syncthreads();

  int wave = tid >> 6, lane = tid & 63;
  int rbase = wave * 16;
  int lrow = rbase + (lane & 15);
  int swz = (lane & 7) << 3;
  bf16x8 a[4];
#pragma unroll
  for (int ks = 0; ks < 4; ++ks)
    a[ks] = *(const bf16x8*)&As[lrow * 128 + ((ks * 32 + (lane >> 4) * 8) ^ swz)];

  f32x4 acc[8];
#pragma unroll
  for (int t = 0; t < 8; ++t) acc[t] = {0.f, 0.f, 0.f, 0.f};
#pragma unroll
  for (int t = 0; t < 8; ++t) {
    int col = t * 16 + (lane & 15);
#pragma unroll
    for (int ks = 0; ks < 4; ++ks) {
      bf16x8 bfr = *(const bf16x8*)&Bs[col * 128 + ((ks * 32 + (lane >> 4) * 8) ^ swz)];
      acc[t] = __builtin_amdgcn_mfma_f32_16x16x32_bf16(a[ks], bfr, acc[t], 0, 0, 0);
    }
  }
#pragma unroll
  for (int t = 0; t < 8; ++t) {
    int col = t * 16 + (lane & 15);
#pragma unroll
    for (int q = 0; q < 4; ++q) {
      int grow = blockRow + rbase + (lane >> 4) * 4 + q;
      if (grow < NN) O[(long)grow * CC + col] = (_Float16)acc[t][q];
    }
  }
}

// ---------------- aggregate: one wave per node; 4-edge unrolled, fdot2, batched gathers ----------------
__global__ __launch_bounds__(256) void k_agg(const _Float16* __restrict__ m,
                                             const _Float16* __restrict__ attr,
                                             const f16x2* __restrict__ ewpk,
                                             const int* __restrict__ src_csr,
                                             const int* __restrict__ rowp,
                                             unsigned short* __restrict__ agg) {
  int n = blockIdx.x * 4 + (threadIdx.x >> 6);   // NN % 4 == 0
  int t = threadIdx.x & 63;
  f16x2 w0[8], w1[8];
#pragma unroll
  for (int kp = 0; kp < 8; ++kp) {
    f16x4 wv = *(const f16x4*)&ewpk[kp * 128 + 2 * t];  // (ch 2t, ch 2t+1)
    w0[kp].x = wv.x; w0[kp].y = wv.y;
    w1[kp].x = wv.z; w1[kp].y = wv.w;
  }
  int b = rowp[n], e = rowp[n + 1];
  union H8 { f16x8 v; f16x2 p[4]; };
  float accA0 = 0.f, accA1 = 0.f, accB0 = 0.f, accB1 = 0.f;

  int i = b;
  // 4-edge unrolled main loop: 4 src + 4 m-gathers + 8 attr16B in flight
  for (; i + 4 <= e; i += 4) {
    int s0 = src_csr[i], s1 = src_csr[i + 1], s2 = src_csr[i + 2], s3 = src_csr[i + 3];
    const f16x8* ap = (const f16x8*)(attr + (long)i * 16);
    H8 A0a, A0b, A1a, A1b, A2a, A2b, A3a, A3b;
    A0a.v = ap[0]; A0b.v = ap[1];
    A1a.v = ap[2]; A1b.v = ap[3];
    A2a.v = ap[4]; A2b.v = ap[5];
    A3a.v = ap[6]; A3b.v = ap[7];
    f16x2 m0 = *(const f16x2*)&m[(long)s0 * CC + 2 * t];
    f16x2 m1 = *(const f16x2*)&m[(long)s1 * CC + 2 * t];
    f16x2 m2 = *(const f16x2*)&m[(long)s2 * CC + 2 * t];
    f16x2 m3 = *(const f16x2*)&m[(long)s3 * CC + 2 * t];
    float d00 = (float)m0.x, d01 = (float)m0.y;
    float d10 = (float)m1.x, d11 = (float)m1.y;
    float d20 = (float)m2.x, d21 = (float)m2.y;
    float d30 = (float)m3.x, d31 = (float)m3.y;
#if HAS_FDOT2
#pragma unroll
    for (int kp = 0; kp < 4; ++kp) {
      d00 = __builtin_amdgcn_fdot2(A0a.p[kp], w0[kp], d00, false);
      d01 = __builtin_amdgcn_fdot2(A0a.p[kp], w1[kp], d01, false);
      d10 = __builtin_amdgcn_fdot2(A1a.p[kp], w0[kp], d10, false);
      d11 = __builtin_amdgcn_fdot2(A1a.p[kp], w1[kp], d11, false);
      d20 = __builtin_amdgcn_fdot2(A2a.p[kp], w0[kp], d20, false);
      d21 = __builtin_amdgcn_fdot2(A2a.p[kp], w1[kp], d21, false);
      d30 = __builtin_amdgcn_fdot2(A3a.p[kp], w0[kp], d30, false);
      d31 = __builtin_amdgcn_fdot2(A3a.p[kp], w1[kp], d31, false);
    }
#pragma unroll
    for (int kp = 0; kp < 4; ++kp) {
      d00 = __builtin_amdgcn_fdot2(A0b.p[kp], w0[4 + kp], d00, false);
      d01 = __builtin_amdgcn_fdot2(A0b.p[kp], w1[4 + kp], d01, false);
      d10 = __builtin_amdgcn_fdot2(A1b.p[kp], w0[4 + kp], d10, false);
      d11 = __builtin_amdgcn_fdot2(A1b.p[kp], w1[4 + kp], d11, false);
      d20 = __builtin_amdgcn_fdot2(A2b.p[kp], w0[4 + kp], d20, false);
      d21 = __builtin_amdgcn_fdot2(A2b.p[kp], w1[4 + kp], d21, false);
      d30 = __builtin_amdgcn_fdot2(A3b.p[kp], w0[4 + kp], d30, false);
      d31 = __builtin_amdgcn_fdot2(A3b.p[kp], w1[4 + kp], d31, false);
    }
#else
#pragma unroll
    for (int kp = 0; kp < 4; ++kp) {
      d00 = fmaf((float)A0a.p[kp].x, (float)w0[kp].x, d00); d00 = fmaf((float)A0a.p[kp].y, (float)w0[kp].y, d00);
      d01 = fmaf((float)A0a.p[kp].x, (float)w1[kp].x, d01); d01 = fmaf((float)A0a.p[kp].y, (float)w1[kp].y, d01);
      d10 = fmaf((float)A1a.p[kp].x, (float)w0[kp].x, d10); d10 = fmaf((float)A1a.p[kp].y, (float)w0[kp].y, d10);
      d11 = fmaf((float)A1a.p[kp].x, (float)w1[kp].x, d11); d11 = fmaf((float)A1a.p[kp].y, (float)w1[kp].y, d11);
      d20 = fmaf((float)A2a.p[kp].x, (float)w0[kp].x, d20); d20 = fmaf((float)A2a.p[kp].y, (float)w0[kp].y, d20);
      d21 = fmaf((float)A2a.p[kp].x, (float)w1[kp].x, d21); d21 = fmaf((float)A2a.p[kp].y, (float)w1[kp].y, d21);
      d30 = fmaf((float)A3a.p[kp].x, (float)w0[kp].x, d30); d30 = fmaf((float)A3a.p[kp].y, (float)w0[kp].y, d30);
      d31 = fmaf((float)A3a.p[kp].x, (float)w1[kp].x, d31); d31 = fmaf((float)A3a.p[kp].y, (float)w1[kp].y, d31);
    }
#pragma unroll
    for (int kp = 0; kp < 4; ++kp) {
      d00 = fmaf((float)A0b.p[kp].x, (float)w0[4 + kp].x, d00); d00 = fmaf((float)A0b.p[kp].y, (float)w0[4 + kp].y, d00);
      d01 = fmaf((float)A0b.p[kp].x, (float)w1[4 + kp].x, d01); d01 = fmaf((float)A0b.p[kp].y, (float)w1[4 + kp].y, d01);
      d10 = fmaf((float)A1b.p[kp].x, (float)w0[4 + kp].x, d10); d10 = fmaf((float)A1b.p[kp].y, (float)w0[4 + kp].y, d10);
      d11 = fmaf((float)A1b.p[kp].x, (float)w1[4 + kp].x, d11); d11 = fmaf((float)A1b.p[kp].y, (float)w1[4 + kp].y, d11);
      d20 = fmaf((float)A2b.p[kp].x, (float)w0[4 + kp].x, d20); d20 = fmaf((float)A2b.p[kp].y, (float)w0[4 + kp].y, d20);
      d21 = fmaf((float)A2b.p[kp].x, (float)w1[4 + kp].x, d21); d21 = fmaf((float)A2b.p[kp].y, (float)w1[4 + kp].y, d21);
      d30 = fmaf((float)A3b.p[kp].x, (float)w0[4 + kp].x, d30); d30 = fmaf((float)A3b.p[kp].y, (float)w0[4 + kp].y, d30);
      d31 = fmaf((float)A3b.p[kp].x, (float)w1[4 + kp].x, d31); d31 = fmaf((float)A3b.p[kp].y, (float)w1[4 + kp].y, d31);
    }
#endif
    accA0 += fmaxf(d00, 0.f); accA1 += fmaxf(d01, 0.f);
    accB0 += fmaxf(d10, 0.f); accB1 += fmaxf(d11, 0.f);
    accA0 += fmaxf(d20, 0.f); accA1 += fmaxf(d21, 0.f);
    accB0 += fmaxf(d30, 0.f); accB1 += fmaxf(d31, 0.f);
  }
  // remainder (0..3 edges)
  for (; i < e; ++i) {
    int s = src_csr[i];
    const f16x8* ap = (const f16x8*)(attr + (long)i * 16);
    H8 Aa, Ab; Aa.v = ap[0]; Ab.v = ap[1];
    f16x2 mp = *(const f16x2*)&m[(long)s * CC + 2 * t];
    float s0 = (float)mp.x, s1 = (float)mp.y;
#if HAS_FDOT2
#pragma unroll
    for (int kp = 0; kp < 4; ++kp) {
      s0 = __builtin_amdgcn_fdot2(Aa.p[kp], w0[kp], s0, false);
      s1 = __builtin_amdgcn_fdot2(Aa.p[kp], w1[kp], s1, false);
    }
#pragma unroll
    for (int kp = 0; kp < 4; ++kp) {
      s0 = __builtin_amdgcn_fdot2(Ab.p[kp], w0[4 + kp], s0, false);
      s1 = __builtin_amdgcn_fdot2(Ab.p[kp], w1[4 + kp], s1, false);
    }
#else
#pragma unroll
    for (int kp = 0; kp < 4; ++kp) {
      s0 = fmaf((float)Aa.p[kp].x, (float)w0[kp].x, s0); s0 = fmaf((float)Aa.p[kp].y, (float)w0[kp].y, s0);
      s1 = fmaf((float)Aa.p[kp].x, (float)w1[kp].x, s1); s1 = fmaf((float)Aa.p[kp].y, (float)w1[kp].y, s1);
      s0 = fmaf((float)Ab.p[kp].x, (float)w0[4 + kp].x, s0); s0 = fmaf((float)Ab.p[kp].y, (float)w0[4 + kp].y, s0);
      s1 = fmaf((float)Ab.p[kp].x, (float)w1[4 + kp].x, s1); s1 = fmaf((float)Ab.p[kp].y, (float)w1[4 + kp].y, s1);
    }
#endif
    accA0 += fmaxf(s0, 0.f);
    accA1 += fmaxf(s1, 0.f);
  }
  float acc0 = accA0 + accB0, acc1 = accA1 + accB1;
  float d = (float)(e - b);
  if (d < 1.f) d = 1.f;
  float inv = 1.f / d;
  unsigned int o = (unsigned int)f2b(acc0 * inv) | ((unsigned int)f2b(acc1 * inv) << 16);
  int cidx = (2 * t) ^ ((n & 7) << 3);
  *(unsigned int*)&agg[(long)n * CC + cidx] = o;
}

// ---------------- fused GRU: BM=64, 512 threads (8 waves), DMA-staged weights ----------------
__global__ __launch_bounds__(512) void k_gru(const unsigned short* __restrict__ aggb,
                                             const unsigned short* __restrict__ hb,
                                             const float* __restrict__ hin,
                                             const unsigned short* __restrict__ wpack,
                                             const float* __restrict__ bih,
                                             const float* __restrict__ bhh,
                                             float* __restrict__ hout,
                                             unsigned short* __restrict__ houtb,
                                             const float* __restrict__ resid) {
  __shared__ __align__(16) unsigned short Sa[64 * 128];       // 16KB
  __shared__ __align__(16) unsigned short Sh[64 * 128];       // 16KB
  __shared__ __align__(16) unsigned short Ws[2 * 128 * 128];  // 64KB: [wih_c | whh_c]
  int tid = threadIdx.x;
  int blockRow = blockIdx.x * 64;

  const unsigned short* sa_src = aggb + (long)blockRow * CC;
  const unsigned short* sh_src = hb + (long)blockRow * CC;
#pragma unroll
  for (int p = 0; p < 2; ++p) {
    int off8 = (p * 512 + tid) * 8;
    gload16(sa_src + off8, Sa + off8);
    gload16(sh_src + off8, Sh + off8);
  }
#pragma unroll
  for (int p = 0; p < 8; ++p) {
    int off8 = (p * 512 + tid) * 8;
    gload16(wpack + off8, Ws + off8);
  }
  __syncthreads();

  int wave = tid >> 6, lane = tid & 63;
  int r0 = (wave >> 1) * 16;   // 0,16,32,48
  int cb = (wave & 1) * 64;    // 0 or 64
  int lrow = r0 + (lane & 15);
  int swz = (lane & 7) << 3;
  bf16x8 aA[4], aH[4];
#pragma unroll
  for (int ks = 0; ks < 4; ++ks) {
    int off = lrow * 128 + ((ks * 32 + (lane >> 4) * 8) ^ swz);
    aA[ks] = *(const bf16x8*)&Sa[off];
    aH[ks] = *(const bf16x8*)&Sh[off];
  }

  float rg[4][4], zg[4][4];

#pragma unroll
  for (int chunk = 0; chunk < 3; ++chunk) {
    f32x4 gi[4], gh[4];
#pragma unroll
    for (int t = 0; t < 4; ++t) { gi[t] = {0.f, 0.f, 0.f, 0.f}; gh[t] = {0.f, 0.f, 0.f, 0.f}; }
#pragma unroll
    for (int t = 0; t < 4; ++t) {
      int col = cb + t * 16 + (lane & 15);
#pragma unroll
      for (int ks = 0; ks < 4; ++ks) {
        int wo = col * 128 + ((ks * 32 + (lane >> 4) * 8) ^ swz);
        bf16x8 bi_ = *(const bf16x8*)&Ws[wo];
        gi[t] = __builtin_amdgcn_mfma_f32_16x16x32_bf16(aA[ks], bi_, gi[t], 0, 0, 0);
        bf16x8 bh_ = *(const bf16x8*)&Ws[16384 + wo];
        gh[t] = __builtin_amdgcn_mfma_f32_16x16x32_bf16(aH[ks], bh_, gh[t], 0, 0, 0);
      }
    }
#pragma unroll
    for (int t = 0; t < 4; ++t) {
      int j = cb + t * 16 + (lane & 15);
      int jg = chunk * 128 + j;
      float bi = bih[jg], bh = bhh[jg];
#pragma unroll
      for (int q = 0; q < 4; ++q) {
        float giv = gi[t][q] + bi;
        float ghv = gh[t][q] + bh;
        if (chunk == 0) {
          rg[t][q] = 1.f / (1.f + __expf(-(giv + ghv)));
        } else if (chunk == 1) {
          zg[t][q] = 1.f / (1.f + __expf(-(giv + ghv)));
        } else {
          float nn = tanhf(giv + rg[t][q] * ghv);
          int grow = blockRow + r0 + (lane >> 4) * 4 + q;
          if (grow < NN) {
            long o = (long)grow * CC + j;
            float h = hin[o];
            float z = zg[t][q];
            float hv = (1.f - z) * nn + z * h;
            if (resid) {
              hout[o] = 0.5f * fmaxf(hv, 0.f) + 0.5f * resid[o];
            } else {
              hout[o] = hv;
              houtb[(long)grow * CC + (j ^ ((grow & 7) << 3))] = f2b(hv);
            }
          }
        }
      }
    }
    if (chunk < 2) {
      __syncthreads();  // all waves done reading Ws
      const unsigned short* wsrc = wpack + (long)(chunk + 1) * 32768;
#pragma unroll
      for (int p = 0; p < 8; ++p) {
        int off8 = (p * 512 + tid) * 8;
        gload16(wsrc + off8, Ws + off8);
      }
      __syncthreads();  // staged (compiler drains vmcnt before barrier)
    }
  }
}

extern "C" void kernel_launch(void* const* d_in, const int* in_sizes, int n_in,
                              void* d_out, int out_size, void* d_ws, size_t ws_size,
                              hipStream_t stream) {
  const float* x     = (const float*)d_in[0];
  const int*   eidx  = (const int*)d_in[1];
  const float* eattr = (const float*)d_in[2];
  const float* gamma = (const float*)d_in[3];
  const float* beta  = (const float*)d_in[4];
  const float* eW    = (const float*)d_in[5];
  const float* convW = (const float*)d_in[6];
  const float* wih   = (const float*)d_in[7];
  const float* whh   = (const float*)d_in[8];
  const float* bih   = (const float*)d_in[9];
  const float* bhh   = (const float*)d_in[10];
  float* out = (float*)d_out;

  char* ws = (char*)d_ws;
  size_t off = 0;
  auto alloc = [&](size_t bytes) -> void* {
    void* p = ws + off;
    off += (bytes + 255) & ~(size_t)255;
    return p;
  };
  float* stats   = (float*)alloc(512 * 4);
  int*   cnt     = (int*)alloc((size_t)NN * 4);
  int*   cursor  = (int*)alloc((size_t)NN * 4);
  int*   rowp    = (int*)alloc((size_t)(NN + 1) * 4);
  int*   blocksum = (int*)alloc(256 * 4);
  int*   blockoff = (int*)alloc(256 * 4);
  int*   src_csr = (int*)alloc((size_t)NE * 4);
  _Float16* attr_csr = (_Float16*)alloc((size_t)NE * 16 * 2);
  float* xh      = (float*)alloc((size_t)NN * CC * 4);
  float* h1      = (float*)alloc((size_t)NN * CC * 4);
  unsigned short* xhb  = (unsigned short*)alloc((size_t)NN64 * CC * 2);
  unsigned short* h1b  = (unsigned short*)alloc((size_t)NN64 * CC * 2);
  _Float16* mb        = (_Float16*)alloc((size_t)NN64 * CC * 2);
  unsigned short* aggb = (unsigned short*)alloc((size_t)NN64 * CC * 2);
  unsigned short* wpack = (unsigned short*)alloc((size_t)98304 * 2);
  unsigned short* cpack = (unsigned short*)alloc((size_t)32768 * 2);
  f16x2* ewpk    = (f16x2*)alloc((size_t)1024 * 4);
  (void)ws_size;

  const int* srcv = eidx;
  const int* dstv = eidx + NE;

  hipMemsetAsync(stats, 0, 256 * 4, stream);
  hipMemsetAsync(cnt, 0, (size_t)NN * 4, stream);
  hipMemsetAsync(cursor, 0, (size_t)NN * 4, stream);

  k_prep<<<516, 256, 0, stream>>>(wih, whh, convW, eW, wpack, cpack, ewpk);
  k_bnstats<<<512, 128, 0, stream>>>(x, stats);
  k_bnfinal<<<1, 128, 0, stream>>>(stats, gamma, beta);
  k_norm<<<2048, 256, 0, stream>>>(x, stats, xh, xhb);

  k_cnt<<<1024, 256, 0, stream>>>(dstv, cnt);
  k_scan_a<<<SCANB, 256, 0, stream>>>(cnt, blocksum);
  k_scan_b<<<1, 256, 0, stream>>>(blocksum, blockoff, rowp);
  k_scan_c<<<SCANB, 256, 0, stream>>>(cnt, blockoff, rowp);
  k_fill<<<1024, 256, 0, stream>>>(dstv, srcv, eattr, rowp, cursor, src_csr, attr_csr);

  // layer 0: h0 = xh
  k_mgemm<<<NN64 / 64, 256, 0, stream>>>(xhb, cpack, mb);
  k_agg<<<NN / 4, 256, 0, stream>>>(mb, attr_csr, ewpk, src_csr, rowp, aggb);
  k_gru<<<NN64 / 64, 512, 0, stream>>>(aggb, xhb, xh, wpack, bih, bhh, h1, h1b, nullptr);

  // layer 1 (+ fused residual epilogue)
  k_mgemm<<<NN64 / 64, 256, 0, stream>>>(h1b, cpack + (size_t)128 * 128, mb);
  k_agg<<<NN / 4, 256, 0, stream>>>(mb, attr_csr, ewpk, src_csr, rowp, aggb);
  k_gru<<<NN64 / 64, 512, 0, stream>>>(aggb, h1b, h1, wpack, bih, bhh, out, nullptr, xh);
}

// Round 10
// 465.730 us; speedup vs baseline: 1.1510x; 1.1510x over previous
//
#include <hip/hip_runtime.h>

#define NN 50000
#define NN64 50048
#define NE 600000
#define CC 128
#define SCANB 196  // ceil(NN/256)

typedef float f32x4 __attribute__((ext_vector_type(4)));
typedef short bf16x8 __attribute__((ext_vector_type(8)));
typedef unsigned short u16x4 __attribute__((ext_vector_type(4)));
typedef _Float16 f16x2 __attribute__((ext_vector_type(2)));
typedef _Float16 f16x4 __attribute__((ext_vector_type(4)));
typedef _Float16 f16x8 __attribute__((ext_vector_type(8)));
typedef int i32x4i __attribute__((ext_vector_type(4)));
typedef int i32x8i __attribute__((ext_vector_type(8)));

#if defined(__has_builtin)
#if __has_builtin(__builtin_amdgcn_fdot2)
#define HAS_FDOT2 1
#endif
#endif

__device__ __forceinline__ unsigned short f2b(float f) {
  union { float f; unsigned int u; } c; c.f = f;
  unsigned int r = c.u + 0x7FFFu + ((c.u >> 16) & 1u);
  return (unsigned short)(r >> 16);
}
// async global->LDS 16B DMA (wave-uniform LDS base + lane*16 semantics; layouts kept linear)
__device__ __forceinline__ void gload16(const unsigned short* g, unsigned short* l) {
  __builtin_amdgcn_global_load_lds((const __attribute__((address_space(1))) void*)g,
                                   (__attribute__((address_space(3))) void*)l, 16, 0, 0);
}

// ---------------- weight prep ----------------
__global__ __launch_bounds__(256) void k_prep(const float* __restrict__ wih,
                                              const float* __restrict__ whh,
                                              const float* __restrict__ convW,
                                              const float* __restrict__ eW,
                                              unsigned short* __restrict__ wpack,
                                              unsigned short* __restrict__ cpack,
                                              f16x2* __restrict__ ewpk) {
  int i = blockIdx.x * 256 + threadIdx.x;
  if (i < 98304) {
    int k = i & 127, j = (i >> 7) & 127, half = (i >> 14) & 1, chunk = i >> 15;
    const float* srcm = half ? whh : wih;
    float v = srcm[(long)(chunk * 128 + j) * CC + k];
    wpack[(long)(((chunk * 2 + half) * 128 + j) << 7) + (k ^ ((j & 7) << 3))] = f2b(v);
  } else if (i < 131072) {
    int i2 = i - 98304;
    int k = i2 & 127, j = (i2 >> 7) & 127, layer = i2 >> 14;
    float v = convW[(long)(layer * 128 + k) * CC + j];
    cpack[(long)((layer * 128 + j) << 7) + (k ^ ((j & 7) << 3))] = f2b(v);
  } else if (i < 132096) {
    int i2 = i - 131072;
    int kp = i2 >> 7, ch = i2 & 127;
    f16x2 w; w.x = (_Float16)eW[(2 * kp) * CC + ch]; w.y = (_Float16)eW[(2 * kp + 1) * CC + ch];
    ewpk[i2] = w;
  }
}

// ---------------- BatchNorm ----------------
__global__ __launch_bounds__(128) void k_bnstats(const float* __restrict__ x,
                                                 float* __restrict__ stats) {
  int c = threadIdx.x;
  float s = 0.f, s2 = 0.f;
  for (int r = blockIdx.x; r < NN; r += gridDim.x) {
    float v = x[(long)r * CC + c];
    s += v; s2 += v * v;
  }
  atomicAdd(&stats[c], s);
  atomicAdd(&stats[CC + c], s2);
}

__global__ __launch_bounds__(128) void k_bnfinal(float* __restrict__ stats,
                                                 const float* __restrict__ gamma,
                                                 const float* __restrict__ beta) {
  int c = threadIdx.x;
  float mean = stats[c] * (1.f / NN);
  float var = stats[CC + c] * (1.f / NN) - mean * mean;
  var = fmaxf(var, 0.f);
  float sc = gamma[c] * rsqrtf(var + 1e-5f);
  stats[2 * CC + c] = sc;
  stats[3 * CC + c] = beta[c] - mean * sc;
}

// writes xh (f32) + xh_b (bf16, row-swizzled, for MFMA DMA staging)
__global__ __launch_bounds__(256) void k_norm(const float* __restrict__ x,
                                              const float* __restrict__ stats,
                                              float* __restrict__ xh,
                                              unsigned short* __restrict__ xhb) {
  const int total4 = NN * CC / 4;
  for (int i = blockIdx.x * 256 + threadIdx.x; i < total4; i += gridDim.x * 256) {
    f32x4 v = ((const f32x4*)x)[i];
    int c4 = (i & 31) * 4;
    int r = i >> 5;
    f32x4 sc = *(const f32x4*)&stats[2 * CC + c4];
    f32x4 sh = *(const f32x4*)&stats[3 * CC + c4];
    v = v * sc + sh;
    ((f32x4*)xh)[i] = v;
    u16x4 b; b.x = f2b(v[0]); b.y = f2b(v[1]); b.z = f2b(v[2]); b.w = f2b(v[3]);
    *(u16x4*)&xhb[(long)r * CC + (c4 ^ ((r & 7) << 3))] = b;
  }
}

// ---------------- CSR build ----------------
__global__ __launch_bounds__(256) void k_cnt(const int* __restrict__ dst, int* __restrict__ cnt) {
  for (int e = blockIdx.x * 256 + threadIdx.x; e < NE; e += gridDim.x * 256)
    atomicAdd(&cnt[dst[e]], 1);
}

// 3-phase multi-block exclusive scan of cnt[NN] -> rowp[NN+1]
__global__ __launch_bounds__(256) void k_scan_a(const int* __restrict__ cnt,
                                                int* __restrict__ blocksum) {
  int t = threadIdx.x, b = blockIdx.x;
  int idx = b * 256 + t;
  int v = (idx < NN) ? cnt[idx] : 0;
#pragma unroll
  for (int off = 32; off; off >>= 1) v += __shfl_down(v, off, 64);
  __shared__ int wsum[4];
  if ((t & 63) == 0) wsum[t >> 6] = v;
  __syncthreads();
  if (t == 0) blocksum[b] = wsum[0] + wsum[1] + wsum[2] + wsum[3];
}

__global__ __launch_bounds__(256) void k_scan_b(const int* __restrict__ blocksum,
                                                int* __restrict__ blockoff,
                                                int* __restrict__ rowp) {
  int t = threadIdx.x;
  int v = (t < SCANB) ? blocksum[t] : 0;
  __shared__ int sd[256];
  sd[t] = v;
  __syncthreads();
  for (int off = 1; off < 256; off <<= 1) {
    int x = (t >= off) ? sd[t - off] : 0;
    __syncthreads();
    sd[t] += x;
    __syncthreads();
  }
  blockoff[t] = sd[t] - v;  // exclusive
  if (t == 255) rowp[NN] = sd[255];
}

__global__ __launch_bounds__(256) void k_scan_c(const int* __restrict__ cnt,
                                                const int* __restrict__ blockoff,
                                                int* __restrict__ rowp) {
  int t = threadIdx.x, b = blockIdx.x;
  int idx = b * 256 + t;
  int v = (idx < NN) ? cnt[idx] : 0;
  __shared__ int sd[256];
  sd[t] = v;
  __syncthreads();
  for (int off = 1; off < 256; off <<= 1) {
    int x = (t >= off) ? sd[t - off] : 0;
    __syncthreads();
    sd[t] += x;
    __syncthreads();
  }
  if (idx < NN) rowp[idx] = blockoff[b] + sd[t] - v;
}

// per edge: write src and f16 edge_attr into CSR (dst-sorted) slots
__global__ __launch_bounds__(256) void k_fill(const int* __restrict__ dst,
                                              const int* __restrict__ src,
                                              const float* __restrict__ eattr,
                                              const int* __restrict__ rowp,
                                              int* __restrict__ cursor,
                                              int* __restrict__ src_csr,
                                              _Float16* __restrict__ attr_csr) {
  for (int e = blockIdx.x * 256 + threadIdx.x; e < NE; e += gridDim.x * 256) {
    int d = dst[e];
    int pos = atomicAdd(&cursor[d], 1);
    int idx = rowp[d] + pos;
    src_csr[idx] = src[e];
    const f32x4* ar = (const f32x4*)(eattr + (long)e * 16);
    f32x4 a0 = ar[0], a1 = ar[1], a2 = ar[2], a3 = ar[3];
    f16x8 h0, h1;
#pragma unroll
    for (int q = 0; q < 4; ++q) { h0[q] = (_Float16)a0[q]; h0[4 + q] = (_Float16)a1[q]; }
#pragma unroll
    for (int q = 0; q < 4; ++q) { h1[q] = (_Float16)a2[q]; h1[4 + q] = (_Float16)a3[q]; }
    f16x8* orow = (f16x8*)&attr_csr[(long)idx * 16];
    orow[0] = h0; orow[1] = h1;
  }
}

// ---------------- m = h @ convW  (bf16 MFMA, BM=64, staging via global_load_lds, f16 out) ----------------
__global__ __launch_bounds__(256) void k_mgemm(const unsigned short* __restrict__ Ab,
                                               const unsigned short* __restrict__ Bp,
                                               _Float16* __restrict__ O) {
  __shared__ __align__(16) unsigned short As[64 * 128];   // 16KB
  __shared__ __align__(16) unsigned short Bs[128 * 128];  // 32KB
  int tid = threadIdx.x;
  int blockRow = blockIdx.x * 64;
  const unsigned short* asrc = Ab + (long)blockRow * CC;
#pragma unroll
  for (int p = 0; p < 4; ++p) {
    int off8 = (p * 256 + tid) * 8;
    gload16(asrc + off8, As + off8);
  }
#pragma unroll
  for (int p = 0; p < 8; ++p) {
    int off8 = (p * 256 + tid) * 8;
    gload16(Bp + off8, Bs + off8);
  }
  __syncthreads();

  int wave = tid >> 6, lane = tid & 63;
  int rbase = wave * 16;
  int lrow = rbase + (lane & 15);
  int swz = (lane & 7) << 3;
  bf16x8 a[4];
#pragma unroll
  for (int ks = 0; ks < 4; ++ks)
    a[ks] = *(const bf16x8*)&As[lrow * 128 + ((ks * 32 + (lane >> 4) * 8) ^ swz)];

  f32x4 acc[8];
#pragma unroll
  for (int t = 0; t < 8; ++t) acc[t] = {0.f, 0.f, 0.f, 0.f};
#pragma unroll
  for (int t = 0; t < 8; ++t) {
    int col = t * 16 + (lane & 15);
#pragma unroll
    for (int ks = 0; ks < 4; ++ks) {
      bf16x8 bfr = *(const bf16x8*)&Bs[col * 128 + ((ks * 32 + (lane >> 4) * 8) ^ swz)];
      acc[t] = __builtin_amdgcn_mfma_f32_16x16x32_bf16(a[ks], bfr, acc[t], 0, 0, 0);
    }
  }
#pragma unroll
  for (int t = 0; t < 8; ++t) {
    int col = t * 16 + (lane & 15);
#pragma unroll
    for (int q = 0; q < 4; ++q) {
      int grow = blockRow + rbase + (lane >> 4) * 4 + q;
      if (grow < NN) O[(long)grow * CC + col] = (_Float16)acc[t][q];
    }
  }
}

// ---------------- aggregate: wave/node; scalar-cache attr+src, vector m-gather only ----------------
union AU { i32x8i v; f16x2 h[8]; };

__global__ __launch_bounds__(256, 8) void k_agg(const _Float16* __restrict__ m,
                                                const _Float16* __restrict__ attr,
                                                const f16x2* __restrict__ ewpk,
                                                const int* __restrict__ src_csr,
                                                const int* __restrict__ rowp,
                                                unsigned short* __restrict__ agg) {
  int n = blockIdx.x * 4 + (threadIdx.x >> 6);   // NN % 4 == 0
  int t = threadIdx.x & 63;
  f16x2 w0[8], w1[8];
#pragma unroll
  for (int kp = 0; kp < 8; ++kp) {
    f16x4 wv = *(const f16x4*)&ewpk[kp * 128 + 2 * t];  // (ch 2t, ch 2t+1)
    w0[kp].x = wv.x; w0[kp].y = wv.y;
    w1[kp].x = wv.z; w1[kp].y = wv.w;
  }
  // wave-uniform bounds, made explicit for the scalar loads below
  int b = __builtin_amdgcn_readfirstlane(rowp[n]);
  int e = __builtin_amdgcn_readfirstlane(rowp[n + 1]);
  float acc0 = 0.f, acc1 = 0.f;

  int i = b;
  for (; i + 4 <= e; i += 4) {
    i32x4i S;
    AU A0, A1, A2, A3;
    asm("s_load_dwordx4 %0, %1, 0x0" : "=s"(S) : "s"(src_csr + i));
    asm("s_load_dwordx8 %0, %1, 0x0" : "=s"(A0.v) : "s"(attr + (size_t)i * 16));
    asm("s_load_dwordx8 %0, %1, 0x0" : "=s"(A1.v) : "s"(attr + (size_t)(i + 1) * 16));
    asm("s_load_dwordx8 %0, %1, 0x0" : "=s"(A2.v) : "s"(attr + (size_t)(i + 2) * 16));
    asm("s_load_dwordx8 %0, %1, 0x0" : "=s"(A3.v) : "s"(attr + (size_t)(i + 3) * 16));
    // consumers below depend on the "+s" outputs of this wait -> cannot hoist (rule #18)
    asm volatile("s_waitcnt lgkmcnt(0)"
                 : "+s"(S), "+s"(A0.v), "+s"(A1.v), "+s"(A2.v), "+s"(A3.v));
    // issue the 4 m-row gathers (only vector-memory ops in the loop)
    f16x2 m0 = *(const f16x2*)(m + (((unsigned)S.x << 7) + 2 * t));
    f16x2 m1 = *(const f16x2*)(m + (((unsigned)S.y << 7) + 2 * t));
    f16x2 m2 = *(const f16x2*)(m + (((unsigned)S.z << 7) + 2 * t));
    f16x2 m3 = *(const f16x2*)(m + (((unsigned)S.w << 7) + 2 * t));
    __builtin_amdgcn_sched_barrier(0);  // pin gather issue before the compute block
    float d00 = 0.f, d01 = 0.f, d10 = 0.f, d11 = 0.f;
    float d20 = 0.f, d21 = 0.f, d30 = 0.f, d31 = 0.f;
#if HAS_FDOT2
#pragma unroll
    for (int kp = 0; kp < 8; ++kp) {
      d00 = __builtin_amdgcn_fdot2(A0.h[kp], w0[kp], d00, false);
      d01 = __builtin_amdgcn_fdot2(A0.h[kp], w1[kp], d01, false);
      d10 = __builtin_amdgcn_fdot2(A1.h[kp], w0[kp], d10, false);
      d11 = __builtin_amdgcn_fdot2(A1.h[kp], w1[kp], d11, false);
      d20 = __builtin_amdgcn_fdot2(A2.h[kp], w0[kp], d20, false);
      d21 = __builtin_amdgcn_fdot2(A2.h[kp], w1[kp], d21, false);
      d30 = __builtin_amdgcn_fdot2(A3.h[kp], w0[kp], d30, false);
      d31 = __builtin_amdgcn_fdot2(A3.h[kp], w1[kp], d31, false);
    }
#else
#pragma unroll
    for (int kp = 0; kp < 8; ++kp) {
      d00 = fmaf((float)A0.h[kp].x, (float)w0[kp].x, d00); d00 = fmaf((float)A0.h[kp].y, (float)w0[kp].y, d00);
      d01 = fmaf((float)A0.h[kp].x, (float)w1[kp].x, d01); d01 = fmaf((float)A0.h[kp].y, (float)w1[kp].y, d01);
      d10 = fmaf((float)A1.h[kp].x, (float)w0[kp].x, d10); d10 = fmaf((float)A1.h[kp].y, (float)w0[kp].y, d10);
      d11 = fmaf((float)A1.h[kp].x, (float)w1[kp].x, d11); d11 = fmaf((float)A1.h[kp].y, (float)w1[kp].y, d11);
      d20 = fmaf((float)A2.h[kp].x, (float)w0[kp].x, d20); d20 = fmaf((float)A2.h[kp].y, (float)w0[kp].y, d20);
      d21 = fmaf((float)A2.h[kp].x, (float)w1[kp].x, d21); d21 = fmaf((float)A2.h[kp].y, (float)w1[kp].y, d21);
      d30 = fmaf((float)A3.h[kp].x, (float)w0[kp].x, d30); d30 = fmaf((float)A3.h[kp].y, (float)w0[kp].y, d30);
      d31 = fmaf((float)A3.h[kp].x, (float)w1[kp].x, d31); d31 = fmaf((float)A3.h[kp].y, (float)w1[kp].y, d31);
    }
#endif
    acc0 += fmaxf(d00 + (float)m0.x, 0.f) + fmaxf(d10 + (float)m1.x, 0.f);
    acc1 += fmaxf(d01 + (float)m0.y, 0.f) + fmaxf(d11 + (float)m1.y, 0.f);
    acc0 += fmaxf(d20 + (float)m2.x, 0.f) + fmaxf(d30 + (float)m3.x, 0.f);
    acc1 += fmaxf(d21 + (float)m2.y, 0.f) + fmaxf(d31 + (float)m3.y, 0.f);
  }
  // remainder (0..3 edges)
  for (; i < e; ++i) {
    int s;
    AU A;
    asm("s_load_dword %0, %1, 0x0" : "=s"(s) : "s"(src_csr + i));
    asm("s_load_dwordx8 %0, %1, 0x0" : "=s"(A.v) : "s"(attr + (size_t)i * 16));
    asm volatile("s_waitcnt lgkmcnt(0)" : "+s"(s), "+s"(A.v));
    f16x2 mv = *(const f16x2*)(m + (((unsigned)s << 7) + 2 * t));
    float d0 = 0.f, d1 = 0.f;
#if HAS_FDOT2
#pragma unroll
    for (int kp = 0; kp < 8; ++kp) {
      d0 = __builtin_amdgcn_fdot2(A.h[kp], w0[kp], d0, false);
      d1 = __builtin_amdgcn_fdot2(A.h[kp], w1[kp], d1, false);
    }
#else
#pragma unroll
    for (int kp = 0; kp < 8; ++kp) {
      d0 = fmaf((float)A.h[kp].x, (float)w0[kp].x, d0); d0 = fmaf((float)A.h[kp].y, (float)w0[kp].y, d0);
      d1 = fmaf((float)A.h[kp].x, (float)w1[kp].x, d1); d1 = fmaf((float)A.h[kp].y, (float)w1[kp].y, d1);
    }
#endif
    acc0 += fmaxf(d0 + (float)mv.x, 0.f);
    acc1 += fmaxf(d1 + (float)mv.y, 0.f);
  }

  float d = (float)(e - b);
  if (d < 1.f) d = 1.f;
  float inv = 1.f / d;
  unsigned int o = (unsigned int)f2b(acc0 * inv) | ((unsigned int)f2b(acc1 * inv) << 16);
  int cidx = (2 * t) ^ ((n & 7) << 3);
  *(unsigned int*)&agg[(long)n * CC + cidx] = o;
}

// ---------------- fused GRU: BM=32, 256 thr (round-8 winner), DMA-staged weights ----------------
__global__ __launch_bounds__(256) void k_gru(const unsigned short* __restrict__ aggb,
                                             const unsigned short* __restrict__ hb,
                                             const float* __restrict__ hin,
                                             const unsigned short* __restrict__ wpack,
                                             const float* __restrict__ bih,
                                             const float* __restrict__ bhh,
                                             float* __restrict__ hout,
                                             unsigned short* __restrict__ houtb,
                                             const float* __restrict__ resid) {
  __shared__ __align__(16) unsigned short Sa[32 * 128];       // 8KB
  __shared__ __align__(16) unsigned short Sh[32 * 128];       // 8KB
  __shared__ __align__(16) unsigned short Ws[2 * 128 * 128];  // 64KB: [wih_c | whh_c]
  int tid = threadIdx.x;
  int blockRow = blockIdx.x * 32;

  const unsigned short* sa_src = aggb + (long)blockRow * CC;
  const unsigned short* sh_src = hb + (long)blockRow * CC;
#pragma unroll
  for (int p = 0; p < 2; ++p) {
    int off8 = (p * 256 + tid) * 8;
    gload16(sa_src + off8, Sa + off8);
    gload16(sh_src + off8, Sh + off8);
  }
#pragma unroll
  for (int p = 0; p < 16; ++p) {
    int off8 = (p * 256 + tid) * 8;
    gload16(wpack + off8, Ws + off8);
  }
  __syncthreads();

  int wave = tid >> 6, lane = tid & 63;
  int r0 = (wave >> 1) * 16;   // 0 or 16
  int cb = (wave & 1) * 64;    // 0 or 64
  int lrow = r0 + (lane & 15);
  int swz = (lane & 7) << 3;
  bf16x8 aA[4], aH[4];
#pragma unroll
  for (int ks = 0; ks < 4; ++ks) {
    int off = lrow * 128 + ((ks * 32 + (lane >> 4) * 8) ^ swz);
    aA[ks] = *(const bf16x8*)&Sa[off];
    aH[ks] = *(const bf16x8*)&Sh[off];
  }

  float rg[4][4], zg[4][4];

#pragma unroll
  for (int chunk = 0; chunk < 3; ++chunk) {
    f32x4 gi[4], gh[4];
#pragma unroll
    for (int t = 0; t < 4; ++t) { gi[t] = {0.f, 0.f, 0.f, 0.f}; gh[t] = {0.f, 0.f, 0.f, 0.f}; }
#pragma unroll
    for (int t = 0; t < 4; ++t) {
      int col = cb + t * 16 + (lane & 15);
#pragma unroll
      for (int ks = 0; ks < 4; ++ks) {
        int wo = col * 128 + ((ks * 32 + (lane >> 4) * 8) ^ swz);
        bf16x8 bi_ = *(const bf16x8*)&Ws[wo];
        gi[t] = __builtin_amdgcn_mfma_f32_16x16x32_bf16(aA[ks], bi_, gi[t], 0, 0, 0);
        bf16x8 bh_ = *(const bf16x8*)&Ws[16384 + wo];
        gh[t] = __builtin_amdgcn_mfma_f32_16x16x32_bf16(aH[ks], bh_, gh[t], 0, 0, 0);
      }
    }
#pragma unroll
    for (int t = 0; t < 4; ++t) {
      int j = cb + t * 16 + (lane & 15);
      int jg = chunk * 128 + j;
      float bi = bih[jg], bh = bhh[jg];
#pragma unroll
      for (int q = 0; q < 4; ++q) {
        float giv = gi[t][q] + bi;
        float ghv = gh[t][q] + bh;
        if (chunk == 0) {
          rg[t][q] = 1.f / (1.f + __expf(-(giv + ghv)));
        } else if (chunk == 1) {
          zg[t][q] = 1.f / (1.f + __expf(-(giv + ghv)));
        } else {
          float nn = tanhf(giv + rg[t][q] * ghv);
          int grow = blockRow + r0 + (lane >> 4) * 4 + q;
          if (grow < NN) {
            long o = (long)grow * CC + j;
            float h = hin[o];
            float z = zg[t][q];
            float hv = (1.f - z) * nn + z * h;
            if (resid) {
              hout[o] = 0.5f * fmaxf(hv, 0.f) + 0.5f * resid[o];
            } else {
              hout[o] = hv;
              houtb[(long)grow * CC + (j ^ ((grow & 7) << 3))] = f2b(hv);
            }
          }
        }
      }
    }
    if (chunk < 2) {
      __syncthreads();  // all waves done reading Ws
      const unsigned short* wsrc = wpack + (long)(chunk + 1) * 32768;
#pragma unroll
      for (int p = 0; p < 16; ++p) {
        int off8 = (p * 256 + tid) * 8;
        gload16(wsrc + off8, Ws + off8);
      }
      __syncthreads();  // staged (compiler drains vmcnt before barrier)
    }
  }
}

extern "C" void kernel_launch(void* const* d_in, const int* in_sizes, int n_in,
                              void* d_out, int out_size, void* d_ws, size_t ws_size,
                              hipStream_t stream) {
  const float* x     = (const float*)d_in[0];
  const int*   eidx  = (const int*)d_in[1];
  const float* eattr = (const float*)d_in[2];
  const float* gamma = (const float*)d_in[3];
  const float* beta  = (const float*)d_in[4];
  const float* eW    = (const float*)d_in[5];
  const float* convW = (const float*)d_in[6];
  const float* wih   = (const float*)d_in[7];
  const float* whh   = (const float*)d_in[8];
  const float* bih   = (const float*)d_in[9];
  const float* bhh   = (const float*)d_in[10];
  float* out = (float*)d_out;

  char* ws = (char*)d_ws;
  size_t off = 0;
  auto alloc = [&](size_t bytes) -> void* {
    void* p = ws + off;
    off += (bytes + 255) & ~(size_t)255;
    return p;
  };
  float* stats   = (float*)alloc(512 * 4);
  int*   cnt     = (int*)alloc((size_t)NN * 4);
  int*   cursor  = (int*)alloc((size_t)NN * 4);
  int*   rowp    = (int*)alloc((size_t)(NN + 1) * 4);
  int*   blocksum = (int*)alloc(256 * 4);
  int*   blockoff = (int*)alloc(256 * 4);
  int*   src_csr = (int*)alloc((size_t)NE * 4);
  _Float16* attr_csr = (_Float16*)alloc((size_t)NE * 16 * 2);
  float* xh      = (float*)alloc((size_t)NN * CC * 4);
  float* h1      = (float*)alloc((size_t)NN * CC * 4);
  unsigned short* xhb  = (unsigned short*)alloc((size_t)NN64 * CC * 2);
  unsigned short* h1b  = (unsigned short*)alloc((size_t)NN64 * CC * 2);
  _Float16* mb        = (_Float16*)alloc((size_t)NN64 * CC * 2);
  unsigned short* aggb = (unsigned short*)alloc((size_t)NN64 * CC * 2);
  unsigned short* wpack = (unsigned short*)alloc((size_t)98304 * 2);
  unsigned short* cpack = (unsigned short*)alloc((size_t)32768 * 2);
  f16x2* ewpk    = (f16x2*)alloc((size_t)1024 * 4);
  (void)ws_size;

  const int* srcv = eidx;
  const int* dstv = eidx + NE;

  hipMemsetAsync(stats, 0, 256 * 4, stream);
  hipMemsetAsync(cnt, 0, (size_t)NN * 4, stream);
  hipMemsetAsync(cursor, 0, (size_t)NN * 4, stream);

  k_prep<<<516, 256, 0, stream>>>(wih, whh, convW, eW, wpack, cpack, ewpk);
  k_bnstats<<<512, 128, 0, stream>>>(x, stats);
  k_bnfinal<<<1, 128, 0, stream>>>(stats, gamma, beta);
  k_norm<<<2048, 256, 0, stream>>>(x, stats, xh, xhb);

  k_cnt<<<1024, 256, 0, stream>>>(dstv, cnt);
  k_scan_a<<<SCANB, 256, 0, stream>>>(cnt, blocksum);
  k_scan_b<<<1, 256, 0, stream>>>(blocksum, blockoff, rowp);
  k_scan_c<<<SCANB, 256, 0, stream>>>(cnt, blockoff, rowp);
  k_fill<<<1024, 256, 0, stream>>>(dstv, srcv, eattr, rowp, cursor, src_csr, attr_csr);

  // layer 0: h0 = xh
  k_mgemm<<<NN64 / 64, 256, 0, stream>>>(xhb, cpack, mb);
  k_agg<<<NN / 4, 256, 0, stream>>>(mb, attr_csr, ewpk, src_csr, rowp, aggb);
  k_gru<<<(NN + 31) / 32, 256, 0, stream>>>(aggb, xhb, xh, wpack, bih, bhh, h1, h1b, nullptr);

  // layer 1 (+ fused residual epilogue)
  k_mgemm<<<NN64 / 64, 256, 0, stream>>>(h1b, cpack + (size_t)128 * 128, mb);
  k_agg<<<NN / 4, 256, 0, stream>>>(mb, attr_csr, ewpk, src_csr, rowp, aggb);
  k_gru<<<(NN + 31) / 32, 256, 0, stream>>>(aggb, h1b, h1, wpack, bih, bhh, out, nullptr, xh);
}